// Round 10
// baseline (455.220 us; speedup 1.0000x reference)
//
#include <hip/hip_runtime.h>
#include <cstdint>

typedef __bf16 bf16x8 __attribute__((ext_vector_type(8)));
typedef float floatx4 __attribute__((ext_vector_type(4)));

// M = 4096 rows, C(K) = 256. ROUND 10 = COUNTER-CAPTURE ROUND.
// The ~40 us GEMM mystery survived 6 structural rewrites; single-total
// readouts are ambiguous (R9: G+P=51 fits both epilogue-guilty and
// kloop-guilty splits). rocprof reports top-5 dispatches BY DURATION and the
// 41 us harness fills monopolize it -- so this round adds x12-repeat probe
// kernels that EXCEED the fills and therefore surface in top-5 WITH COUNTERS:
//   probe_kloop  x12: exact reg-dbuf K-loop (loads+MFMA). dur/12 = P.
//   probe_epi    x12: exact shfl-chain epilogue (synthetic acc). dur/12 = E.
//   probe_epi2   x12: candidate fix epilogue (per-lane, no shfl, coalesced
//                     float2 partial stores). dur/12 = E2 (likely <42/12 ->
//                     absent from top-5 = itself a readout).
// Real verified pipeline (R9: transpose + gemm_wave2 + combine_rows) runs
// unchanged first. dur_us is sacrificed this round for information.
//
// Staged layout: Xs[rb(32)][s(4)][kk(2)][rowhi(8)][quad(4)][rowlo(16)][8 bf16]
// holding X[row = rb*128+rowhi*16+rowlo][k = s*64+kk*32+quad*8+j].

#define OFF_X     (0u)
#define OFF_Y     (2u*1024*1024)
#define OFF_PMAX  (4u*1024*1024)
#define OFF_PSUM  (5u*1024*1024)
#define OFF_DIAG  (6u*1024*1024)
#define OFF_LPART (OFF_DIAG + 16384u)
#define OFF_CPART (OFF_LPART + 256u)
#define OFF_CNT   (OFF_CPART + 256u)
#define OFF_SINK  (16u*1024*1024)      // probe_kloop sink (4 MB)
#define OFF_SPM   (24u*1024*1024)      // probe_epi pmax scratch (2 MB w/parity)
#define OFF_SPS   (28u*1024*1024)      // probe_epi psum scratch (2 MB w/parity)
#define OFF_SDG   (30u*1024*1024)      // probe_epi diag scratch
#define OFF_SE2   (32u*1024*1024)      // probe_epi2 scratch (64 MB w/parity)

// ---------------------------------------------------------------------------
// K0: fp32 -> staged bf16 (verified, unchanged).
// ---------------------------------------------------------------------------
__global__ __launch_bounds__(256) void transpose_stage(
    const float* __restrict__ pred, const float* __restrict__ gt,
    unsigned short* __restrict__ Xs, unsigned short* __restrict__ Ys,
    int* __restrict__ cnt) {
  int blk = blockIdx.x;
  const int t = threadIdx.x;
  if (blk == 0 && t < 33) cnt[t] = 0;
  const float* src;
  unsigned short* dst;
  int slab;
  if (blk < 256) { src = pred; dst = Xs; slab = blk; }
  else           { src = gt;   dst = Ys; slab = blk - 256; }
  const float* sb = src + slab * 4096;
  const int rb = slab >> 3, rowhi = slab & 7;
  #pragma unroll
  for (int half = 0; half < 2; ++half) {
    int c_ = half * 256 + t;
    int rowlo = c_ & 15;
    int quad  = (c_ >> 4) & 3;
    int kk    = (c_ >> 6) & 1;
    int s     = c_ >> 7;
    int k0 = s * 64 + kk * 32 + quad * 8;
    unsigned int packed[4];
    #pragma unroll
    for (int jj = 0; jj < 4; ++jj) {
      unsigned int lohi[2];
      #pragma unroll
      for (int e = 0; e < 2; ++e) {
        float f = sb[(k0 + jj * 2 + e) * 16 + rowlo];
        unsigned int u = __float_as_uint(f);
        lohi[e] = (u + 0x7FFFu + ((u >> 16) & 1u)) >> 16;   // RNE -> bf16
      }
      packed[jj] = lohi[0] | (lohi[1] << 16);
    }
    unsigned short* o = dst + rb * 32768 +
        (unsigned)(s * 1024 + kk * 512 + rowhi * 64 + quad * 16 + rowlo) * 8;
    uint4 v; v.x = packed[0]; v.y = packed[1]; v.z = packed[2]; v.w = packed[3];
    *reinterpret_cast<uint4*>(o) = v;
  }
}

#define WAVE_MAP()                                                           \
  const int t = threadIdx.x;                                                 \
  const int wv = t >> 6, lane = t & 63;                                      \
  const int b = blockIdx.x;                                                  \
  const int xcd = b & 7, slot = b >> 3;                                      \
  const int rowb = ((xcd >> 1) << 4) | (slot & 15);                          \
  const int colb = ((xcd & 1) << 3) | (slot >> 4);                           \
  const int hh = rowb & 1, ch = wv & 1;                                      \
  const unsigned short* Ab = Xs + (rowb >> 1) * 32768 + (unsigned)lane * 8;  \
  const unsigned short* Bb = Ys + ((colb << 1) | (wv >> 1)) * 32768 +        \
                             (unsigned)lane * 8;

#define KOFF(KS) ((unsigned)((((KS) >> 1) * 1024 + ((KS)&1) * 512)) * 8)

#define LOADF(AR, BR, KS) do {                                               \
    _Pragma("unroll") for (int fr = 0; fr < 4; ++fr)                         \
      AR[fr] = *reinterpret_cast<const bf16x8*>(                             \
          Ab + KOFF(KS) + (unsigned)((hh * 4 + fr) * 64) * 8);               \
    _Pragma("unroll") for (int fc = 0; fc < 4; ++fc)                         \
      BR[fc] = *reinterpret_cast<const bf16x8*>(                             \
          Bb + KOFF(KS) + (unsigned)((ch * 4 + fc) * 64) * 8);               \
  } while (0)

#define MM(AR, BR) do {                                                      \
    _Pragma("unroll") for (int fr = 0; fr < 4; ++fr)                         \
      _Pragma("unroll") for (int fc = 0; fc < 4; ++fc)                       \
        acc[fr][fc] = __builtin_amdgcn_mfma_f32_16x16x32_bf16(               \
            AR[fr], BR[fc], acc[fr][fc], 0, 0, 0);                           \
  } while (0)

#define KLOOP_DBUF() do {                                                    \
    bf16x8 a0[4], b0[4], a1[4], b1[4];                                       \
    LOADF(a0, b0, 0);                                                        \
    LOADF(a1, b1, 1); MM(a0, b0);                                            \
    LOADF(a0, b0, 2); MM(a1, b1);                                            \
    LOADF(a1, b1, 3); MM(a0, b0);                                            \
    LOADF(a0, b0, 4); MM(a1, b1);                                            \
    LOADF(a1, b1, 5); MM(a0, b0);                                            \
    LOADF(a0, b0, 6); MM(a1, b1);                                            \
    LOADF(a1, b1, 7); MM(a0, b0);                                            \
    MM(a1, b1);                                                              \
  } while (0)

// ---------------------------------------------------------------------------
// K1: real GEMM (R9 gemm_wave2, verified, unchanged).
// ---------------------------------------------------------------------------
__global__ __launch_bounds__(256, 2) void gemm_wave2(
    const unsigned short* __restrict__ Xs, const unsigned short* __restrict__ Ys,
    float* __restrict__ pmax, float* __restrict__ psum, float* __restrict__ diag) {
  WAVE_MAP();
  floatx4 acc[4][4];
  const floatx4 zero = {0.f, 0.f, 0.f, 0.f};
  #pragma unroll
  for (int i = 0; i < 4; ++i)
    #pragma unroll
    for (int j = 0; j < 4; ++j) acc[i][j] = zero;

  KLOOP_DBUF();

  const int quad = lane >> 4, lc = lane & 15;

  if (colb * 4 + wv == rowb) {
    #pragma unroll
    for (int fr = 0; fr < 4; ++fr)
      #pragma unroll
      for (int r = 0; r < 4; ++r)
        if (lc == quad * 4 + r)
          diag[rowb * 64 + fr * 16 + lc] = acc[fr][fr][r];
  }

  #pragma unroll
  for (int fr = 0; fr < 4; ++fr) {
    #pragma unroll
    for (int r = 0; r < 4; ++r) {
      float v0 = acc[fr][0][r], v1 = acc[fr][1][r];
      float v2 = acc[fr][2][r], v3 = acc[fr][3][r];
      float m = fmaxf(fmaxf(v0, v1), fmaxf(v2, v3));
      #pragma unroll
      for (int sh = 1; sh < 16; sh <<= 1) m = fmaxf(m, __shfl_xor(m, sh, 64));
      float ss = __expf(v0 - m) + __expf(v1 - m) +
                 __expf(v2 - m) + __expf(v3 - m);
      #pragma unroll
      for (int sh = 1; sh < 16; sh <<= 1) ss += __shfl_xor(ss, sh, 64);
      if (lc == 0) {
        int grow = rowb * 64 + fr * 16 + quad * 4 + r;
        int p = grow * 64 + colb * 4 + wv;
        pmax[p] = m; psum[p] = ss;
      }
    }
  }
}

// ---------------------------------------------------------------------------
// K2: per-row combine + fused finalize (verified, unchanged).
// ---------------------------------------------------------------------------
__global__ __launch_bounds__(256) void combine_rows(
    const float* __restrict__ pmax, const float* __restrict__ psum,
    const float* __restrict__ diag,
    float* __restrict__ lpart, float* __restrict__ cpart,
    int* __restrict__ cnt, float* __restrict__ out) {
  int row = blockIdx.x * 256 + threadIdx.x;
  const float* pm = pmax + row * 64;
  const float* ps = psum + row * 64;
  float M = -3.4e38f;
  #pragma unroll 8
  for (int b = 0; b < 64; ++b) M = fmaxf(M, pm[b]);
  float S = 0.f;
  #pragma unroll 8
  for (int b = 0; b < 64; ++b) S += ps[b] * __expf(pm[b] - M);
  float d = diag[row];
  float lossr = logf(S) + M - d;
  float corr = (d == M) ? 1.f : 0.f;
  #pragma unroll
  for (int sh = 1; sh < 64; sh <<= 1) {
    lossr += __shfl_xor(lossr, sh, 64);
    corr  += __shfl_xor(corr,  sh, 64);
  }
  __shared__ float ls[4], cs[4];
  int wave = threadIdx.x >> 6, lane = threadIdx.x & 63;
  if (lane == 0) { ls[wave] = lossr; cs[wave] = corr; }
  __syncthreads();
  if (threadIdx.x == 0) {
    lpart[blockIdx.x] = ls[0] + ls[1] + ls[2] + ls[3];
    cpart[blockIdx.x] = cs[0] + cs[1] + cs[2] + cs[3];
    __threadfence();
    if (atomicAdd(cnt, 1) == 15) {
      __threadfence();
      float L = 0.f, C = 0.f;
      for (int i = 0; i < 16; ++i) { L += lpart[i]; C += cpart[i]; }
      out[0] = L * (1.f / 4096.f);
      out[1] = C * (100.f / 4096.f);
    }
  }
}

// ---------------------------------------------------------------------------
// PROBE A: K-loop x12 (loads+MFMA only). dur/12 = P. Enters top-5 if P>3.5.
// ---------------------------------------------------------------------------
__global__ __launch_bounds__(256, 2) void probe_kloop(
    const unsigned short* __restrict__ Xs, const unsigned short* __restrict__ Ys,
    float* __restrict__ sink) {
  WAVE_MAP();
  floatx4 total = {0.f, 0.f, 0.f, 0.f};
  #pragma unroll 1
  for (int rep = 0; rep < 12; ++rep) {
    floatx4 acc[4][4];
    const floatx4 zero = {0.f, 0.f, 0.f, 0.f};
    #pragma unroll
    for (int i = 0; i < 4; ++i)
      #pragma unroll
      for (int j = 0; j < 4; ++j) acc[i][j] = zero;
    KLOOP_DBUF();
    #pragma unroll
    for (int i = 0; i < 4; ++i)
      #pragma unroll
      for (int j = 0; j < 4; ++j) total += acc[i][j];
  }
  *reinterpret_cast<floatx4*>(sink + (size_t)(b * 256 + t) * 4) = total;
}

// ---------------------------------------------------------------------------
// PROBE B: shfl-chain epilogue x12 on synthetic acc. dur/12 = E.
// Byte-identical reduce/store structure to gemm_wave2's epilogue.
// ---------------------------------------------------------------------------
__global__ __launch_bounds__(256, 2) void probe_epi(
    const unsigned short* __restrict__ Xs, const unsigned short* __restrict__ Ys,
    float* __restrict__ spmax, float* __restrict__ spsum,
    float* __restrict__ sdiag) {
  WAVE_MAP();
  (void)Ab; (void)Bb;
  const int quad = lane >> 4, lc = lane & 15;
  #pragma unroll 1
  for (int rep = 0; rep < 12; ++rep) {
    floatx4 acc[4][4];
    #pragma unroll
    for (int i = 0; i < 4; ++i)
      #pragma unroll
      for (int j = 0; j < 4; ++j) {
        float base = (float)(lane + rep + i * 4 + j) * 1e-3f;
        acc[i][j][0] = base; acc[i][j][1] = base + 0.25f;
        acc[i][j][2] = base + 0.5f; acc[i][j][3] = base + 0.75f;
      }
    unsigned par = (unsigned)(rep & 1) * 262144u;
    if (colb * 4 + wv == rowb) {
      #pragma unroll
      for (int fr = 0; fr < 4; ++fr)
        #pragma unroll
        for (int r = 0; r < 4; ++r)
          if (lc == quad * 4 + r)
            sdiag[(rep & 1) * 4096 + rowb * 64 + fr * 16 + lc] = acc[fr][fr][r];
    }
    #pragma unroll
    for (int fr = 0; fr < 4; ++fr) {
      #pragma unroll
      for (int r = 0; r < 4; ++r) {
        float v0 = acc[fr][0][r], v1 = acc[fr][1][r];
        float v2 = acc[fr][2][r], v3 = acc[fr][3][r];
        float m = fmaxf(fmaxf(v0, v1), fmaxf(v2, v3));
        #pragma unroll
        for (int sh = 1; sh < 16; sh <<= 1) m = fmaxf(m, __shfl_xor(m, sh, 64));
        float ss = __expf(v0 - m) + __expf(v1 - m) +
                   __expf(v2 - m) + __expf(v3 - m);
        #pragma unroll
        for (int sh = 1; sh < 16; sh <<= 1) ss += __shfl_xor(ss, sh, 64);
        if (lc == 0) {
          int grow = rowb * 64 + fr * 16 + quad * 4 + r;
          unsigned p = par + (unsigned)(grow * 64 + colb * 4 + wv);
          spmax[p] = m; spsum[p] = ss;
        }
      }
    }
  }
}

// ---------------------------------------------------------------------------
// PROBE C: candidate-fix epilogue x12: per-lane partials (max/sumexp over the
// lane's own 4 values), NO cross-lane ops, NO divergence, coalesced float2
// stores. dur/12 = E2 (expected ~1 us -> absent from top-5 = confirmation).
// ---------------------------------------------------------------------------
__global__ __launch_bounds__(256, 2) void probe_epi2(
    const unsigned short* __restrict__ Xs, const unsigned short* __restrict__ Ys,
    float2* __restrict__ se2) {
  WAVE_MAP();
  (void)Ab; (void)Bb;
  #pragma unroll 1
  for (int rep = 0; rep < 12; ++rep) {
    floatx4 acc[4][4];
    #pragma unroll
    for (int i = 0; i < 4; ++i)
      #pragma unroll
      for (int j = 0; j < 4; ++j) {
        float base = (float)(lane + rep + i * 4 + j) * 1e-3f;
        acc[i][j][0] = base; acc[i][j][1] = base + 0.25f;
        acc[i][j][2] = base + 0.5f; acc[i][j][3] = base + 0.75f;
      }
    size_t lbase = ((size_t)(rep & 1) * 262144u + (size_t)(b * 4 + wv)) * 0 +
                   ((size_t)(rep & 1) * 4194304u) +
                   ((size_t)(b * 4 + wv) * 64 + lane) * 16;
    #pragma unroll
    for (int fr = 0; fr < 4; ++fr) {
      #pragma unroll
      for (int r = 0; r < 4; ++r) {
        float v0 = acc[fr][0][r], v1 = acc[fr][1][r];
        float v2 = acc[fr][2][r], v3 = acc[fr][3][r];
        float m = fmaxf(fmaxf(v0, v1), fmaxf(v2, v3));
        float ss = __expf(v0 - m) + __expf(v1 - m) +
                   __expf(v2 - m) + __expf(v3 - m);
        se2[lbase + fr * 4 + r] = make_float2(m, ss);
      }
    }
  }
}

extern "C" void kernel_launch(void* const* d_in, const int* in_sizes, int n_in,
                              void* d_out, int out_size, void* d_ws, size_t ws_size,
                              hipStream_t stream) {
  const float* pred = (const float*)d_in[0];
  const float* gt   = (const float*)d_in[1];
  char* w = (char*)d_ws;
  unsigned short* Xbf = (unsigned short*)(w + OFF_X);
  unsigned short* Ybf = (unsigned short*)(w + OFF_Y);
  float* pmax  = (float*)(w + OFF_PMAX);
  float* psum  = (float*)(w + OFF_PSUM);
  float* diag  = (float*)(w + OFF_DIAG);
  float* lpart = (float*)(w + OFF_LPART);
  float* cpart = (float*)(w + OFF_CPART);
  int*   cnt   = (int*)(w + OFF_CNT);
  float* sink  = (float*)(w + OFF_SINK);
  float* spm   = (float*)(w + OFF_SPM);
  float* sps   = (float*)(w + OFF_SPS);
  float* sdg   = (float*)(w + OFF_SDG);
  float2* se2  = (float2*)(w + OFF_SE2);
  float* out   = (float*)d_out;

  transpose_stage<<<512, 256, 0, stream>>>(pred, gt, Xbf, Ybf, cnt);
  gemm_wave2<<<1024, 256, 0, stream>>>(Xbf, Ybf, pmax, psum, diag);
  combine_rows<<<16, 256, 0, stream>>>(pmax, psum, diag, lpart, cpart, cnt, out);
  // Diagnostics (top-5 counter capture):
  probe_kloop<<<1024, 256, 0, stream>>>(Xbf, Ybf, sink);
  probe_epi<<<1024, 256, 0, stream>>>(Xbf, Ybf, spm, sps, sdg);
  probe_epi2<<<1024, 256, 0, stream>>>(Xbf, Ybf, se2);
}

// Round 11
// 103.004 us; speedup vs baseline: 4.4194x; 4.4194x over previous
//
#include <hip/hip_runtime.h>
#include <cstdint>

typedef __bf16 bf16x8 __attribute__((ext_vector_type(8)));
typedef float floatx4 __attribute__((ext_vector_type(4)));

// M = 4096 rows, C(K) = 256. ROUND 11: runtime XCD-pinned tile assignment.
// R10 counters identified the ~40 us GEMM mystery: the K-loop over-fetches
// ~3.4x past L2 (41 MB/rep vs 12 MB ideal; 490 MB/12-rep dispatch) and that
// traffic is served at only ~3 TB/s aggregate (L2<->LLC path), i.e. the
// static b&7 XCD swizzle does NOT match actual block->XCD dispatch.
// Fix: each block reads its REAL XCD via s_getreg(HW_REG_XCC_ID) [HW-verified
// gfx950, learn_hip m09] and claims a tile in that XCD's own 16x8 tile region
// (per-XCD atomic slot counter + claim flags + spill fallback: exactly-once
// coverage under any dispatch; duplicate compute would be benign/idempotent).
// Per-XCD panel working set = 1.5 MB -> L2-resident by construction.
// K-loop / epilogue / combine unchanged from verified R9 kernel.
//
// Staged layout: Xs[rb(32)][s(4)][kk(2)][rowhi(8)][quad(4)][rowlo(16)][8 bf16]
// holding X[row = rb*128+rowhi*16+rowlo][k = s*64+kk*32+quad*8+j].
// Fragment for 16-row group rowhi at K-step (s,kk): lane reads 16 B at
//   Xs + rb*32768 + (s*1024 + kk*512 + rowhi*64 + lane)*8.

#define OFF_X     (0u)
#define OFF_Y     (2u*1024*1024)
#define OFF_PMAX  (4u*1024*1024)
#define OFF_PSUM  (5u*1024*1024)
#define OFF_DIAG  (6u*1024*1024)
#define OFF_LPART (OFF_DIAG + 16384u)
#define OFF_CPART (OFF_LPART + 256u)
#define OFF_CNT   (OFF_CPART + 256u)
// int layout at OFF_CNT: [0]=combine cnt, [1..8]=per-XCD slot counters,
// [9]=spill counter, [64..1087]=claim flags (1024 tiles).  (1088 ints)

// ---------------------------------------------------------------------------
// K0: fp32 -> staged bf16 (verified, unchanged except zeroing 1088 ints).
// ---------------------------------------------------------------------------
__global__ __launch_bounds__(256) void transpose_stage(
    const float* __restrict__ pred, const float* __restrict__ gt,
    unsigned short* __restrict__ Xs, unsigned short* __restrict__ Ys,
    int* __restrict__ cnt) {
  int blk = blockIdx.x;
  const int t = threadIdx.x;
  if (blk == 0) {
    for (int i = t; i < 1088; i += 256) cnt[i] = 0;
  }
  const float* src;
  unsigned short* dst;
  int slab;
  if (blk < 256) { src = pred; dst = Xs; slab = blk; }
  else           { src = gt;   dst = Ys; slab = blk - 256; }
  const float* sb = src + slab * 4096;
  const int rb = slab >> 3, rowhi = slab & 7;
  #pragma unroll
  for (int half = 0; half < 2; ++half) {
    int c_ = half * 256 + t;
    int rowlo = c_ & 15;
    int quad  = (c_ >> 4) & 3;
    int kk    = (c_ >> 6) & 1;
    int s     = c_ >> 7;
    int k0 = s * 64 + kk * 32 + quad * 8;
    unsigned int packed[4];
    #pragma unroll
    for (int jj = 0; jj < 4; ++jj) {
      unsigned int lohi[2];
      #pragma unroll
      for (int e = 0; e < 2; ++e) {
        float f = sb[(k0 + jj * 2 + e) * 16 + rowlo];
        unsigned int u = __float_as_uint(f);
        lohi[e] = (u + 0x7FFFu + ((u >> 16) & 1u)) >> 16;   // RNE -> bf16
      }
      packed[jj] = lohi[0] | (lohi[1] << 16);
    }
    unsigned short* o = dst + rb * 32768 +
        (unsigned)(s * 1024 + kk * 512 + rowhi * 64 + quad * 16 + rowlo) * 8;
    uint4 v; v.x = packed[0]; v.y = packed[1]; v.z = packed[2]; v.w = packed[3];
    *reinterpret_cast<uint4*>(o) = v;
  }
}

#define KOFF(KS) ((unsigned)((((KS) >> 1) * 1024 + ((KS)&1) * 512)) * 8)

#define LOADF(AR, BR, KS) do {                                               \
    _Pragma("unroll") for (int fr = 0; fr < 4; ++fr)                         \
      AR[fr] = *reinterpret_cast<const bf16x8*>(                             \
          Ab + KOFF(KS) + (unsigned)((hh * 4 + fr) * 64) * 8);               \
    _Pragma("unroll") for (int fc = 0; fc < 4; ++fc)                         \
      BR[fc] = *reinterpret_cast<const bf16x8*>(                             \
          Bb + KOFF(KS) + (unsigned)((ch * 4 + fc) * 64) * 8);               \
  } while (0)

#define MM(AR, BR) do {                                                      \
    _Pragma("unroll") for (int fr = 0; fr < 4; ++fr)                         \
      _Pragma("unroll") for (int fc = 0; fc < 4; ++fc)                       \
        acc[fr][fc] = __builtin_amdgcn_mfma_f32_16x16x32_bf16(               \
            AR[fr], BR[fc], acc[fr][fc], 0, 0, 0);                           \
  } while (0)

#define KLOOP_DBUF() do {                                                    \
    bf16x8 a0[4], b0[4], a1[4], b1[4];                                       \
    LOADF(a0, b0, 0);                                                        \
    LOADF(a1, b1, 1); MM(a0, b0);                                            \
    LOADF(a0, b0, 2); MM(a1, b1);                                            \
    LOADF(a1, b1, 3); MM(a0, b0);                                            \
    LOADF(a0, b0, 4); MM(a1, b1);                                            \
    LOADF(a1, b1, 5); MM(a0, b0);                                            \
    LOADF(a0, b0, 6); MM(a1, b1);                                            \
    LOADF(a1, b1, 7); MM(a0, b0);                                            \
    MM(a1, b1);                                                              \
  } while (0)

// ---------------------------------------------------------------------------
// K1: per-wave 64x64 GEMM tile, no LDS, no K-loop barriers; runtime
// XCD-pinned tile claim. Tile id tau in [0,1024): region xcd = tau>>7,
// local = tau&127; rowb = (xcd>>1)*16 + (local>>3); colb = (xcd&1)*8 +
// (local&7). Slot order sweeps colb under fixed rowb (A panel temporal
// reuse); per-XCD working set: A 16x32KB + B 8x128KB = 1.5 MB (L2-resident).
// ---------------------------------------------------------------------------
__global__ __launch_bounds__(256, 2) void gemm_wave3(
    const unsigned short* __restrict__ Xs, const unsigned short* __restrict__ Ys,
    float* __restrict__ pmax, float* __restrict__ psum, float* __restrict__ diag,
    int* __restrict__ cnt) {
  const int t = threadIdx.x;
  const int wv = t >> 6, lane = t & 63;

  __shared__ int s_tile;
  if (t == 0) {
    unsigned x;
    asm volatile("s_getreg_b32 %0, hwreg(HW_REG_XCC_ID)" : "=s"(x));
    x &= 7u;
    int* xslot = cnt + 1;        // [1..8]
    int* spill = cnt + 9;
    int* claim = cnt + 64;       // [64..1087]
    int s = atomicAdd(&xslot[x], 1);
    int tile = -1;
    if (s < 128) {
      int cand = (int)(x * 128u + (unsigned)s);
      if (atomicExch(&claim[cand], 1) == 0) tile = cand;
    }
    while (tile < 0) {
      int o = atomicAdd(spill, 1) & 1023;
      if (atomicExch(&claim[o], 1) == 0) tile = o;
    }
    s_tile = tile;
  }
  __syncthreads();
  const int tile = s_tile;
  const int xr = tile >> 7, local = tile & 127;
  const int rowb = ((xr >> 1) << 4) | (local >> 3);
  const int colb = ((xr & 1) << 3) | (local & 7);

  const int hh = rowb & 1, ch = wv & 1;
  const unsigned short* Ab = Xs + (rowb >> 1) * 32768 + (unsigned)lane * 8;
  const unsigned short* Bb = Ys + ((colb << 1) | (wv >> 1)) * 32768 +
                             (unsigned)lane * 8;

  floatx4 acc[4][4];
  const floatx4 zero = {0.f, 0.f, 0.f, 0.f};
  #pragma unroll
  for (int i = 0; i < 4; ++i)
    #pragma unroll
    for (int j = 0; j < 4; ++j) acc[i][j] = zero;

  KLOOP_DBUF();

  const int quad = lane >> 4, lc = lane & 15;

  // Diagonal: wave is on the diagonal iff colb*4 + wv == rowb.
  if (colb * 4 + wv == rowb) {
    #pragma unroll
    for (int fr = 0; fr < 4; ++fr)
      #pragma unroll
      for (int r = 0; r < 4; ++r)
        if (lc == quad * 4 + r)
          diag[rowb * 64 + fr * 16 + lc] = acc[fr][fr][r];
  }

  // Per-row partials over this wave's 64 cols.
  #pragma unroll
  for (int fr = 0; fr < 4; ++fr) {
    #pragma unroll
    for (int r = 0; r < 4; ++r) {
      float v0 = acc[fr][0][r], v1 = acc[fr][1][r];
      float v2 = acc[fr][2][r], v3 = acc[fr][3][r];
      float m = fmaxf(fmaxf(v0, v1), fmaxf(v2, v3));
      #pragma unroll
      for (int sh = 1; sh < 16; sh <<= 1) m = fmaxf(m, __shfl_xor(m, sh, 64));
      float ss = __expf(v0 - m) + __expf(v1 - m) +
                 __expf(v2 - m) + __expf(v3 - m);
      #pragma unroll
      for (int sh = 1; sh < 16; sh <<= 1) ss += __shfl_xor(ss, sh, 64);
      if (lc == 0) {
        int grow = rowb * 64 + fr * 16 + quad * 4 + r;
        int p = grow * 64 + colb * 4 + wv;
        pmax[p] = m; psum[p] = ss;
      }
    }
  }
}

// ---------------------------------------------------------------------------
// K2: per-row combine + fused finalize (verified, unchanged).
// ---------------------------------------------------------------------------
__global__ __launch_bounds__(256) void combine_rows(
    const float* __restrict__ pmax, const float* __restrict__ psum,
    const float* __restrict__ diag,
    float* __restrict__ lpart, float* __restrict__ cpart,
    int* __restrict__ cnt, float* __restrict__ out) {
  int row = blockIdx.x * 256 + threadIdx.x;
  const float* pm = pmax + row * 64;
  const float* ps = psum + row * 64;
  float M = -3.4e38f;
  #pragma unroll 8
  for (int b = 0; b < 64; ++b) M = fmaxf(M, pm[b]);
  float S = 0.f;
  #pragma unroll 8
  for (int b = 0; b < 64; ++b) S += ps[b] * __expf(pm[b] - M);
  float d = diag[row];
  float lossr = logf(S) + M - d;
  float corr = (d == M) ? 1.f : 0.f;
  #pragma unroll
  for (int sh = 1; sh < 64; sh <<= 1) {
    lossr += __shfl_xor(lossr, sh, 64);
    corr  += __shfl_xor(corr,  sh, 64);
  }
  __shared__ float ls[4], cs[4];
  int wave = threadIdx.x >> 6, lane = threadIdx.x & 63;
  if (lane == 0) { ls[wave] = lossr; cs[wave] = corr; }
  __syncthreads();
  if (threadIdx.x == 0) {
    lpart[blockIdx.x] = ls[0] + ls[1] + ls[2] + ls[3];
    cpart[blockIdx.x] = cs[0] + cs[1] + cs[2] + cs[3];
    __threadfence();                     // release per-block partial
    if (atomicAdd(cnt, 1) == 15) {       // last arriver finalizes
      __threadfence();                   // acquire all partials
      float L = 0.f, C = 0.f;
      for (int i = 0; i < 16; ++i) { L += lpart[i]; C += cpart[i]; }
      out[0] = L * (1.f / 4096.f);
      out[1] = C * (100.f / 4096.f);
    }
  }
}

extern "C" void kernel_launch(void* const* d_in, const int* in_sizes, int n_in,
                              void* d_out, int out_size, void* d_ws, size_t ws_size,
                              hipStream_t stream) {
  const float* pred = (const float*)d_in[0];
  const float* gt   = (const float*)d_in[1];
  char* w = (char*)d_ws;
  unsigned short* Xbf = (unsigned short*)(w + OFF_X);
  unsigned short* Ybf = (unsigned short*)(w + OFF_Y);
  float* pmax  = (float*)(w + OFF_PMAX);
  float* psum  = (float*)(w + OFF_PSUM);
  float* diag  = (float*)(w + OFF_DIAG);
  float* lpart = (float*)(w + OFF_LPART);
  float* cpart = (float*)(w + OFF_CPART);
  int*   cnt   = (int*)(w + OFF_CNT);
  float* out   = (float*)d_out;

  transpose_stage<<<512, 256, 0, stream>>>(pred, gt, Xbf, Ybf, cnt);
  gemm_wave3<<<1024, 256, 0, stream>>>(Xbf, Ybf, pmax, psum, diag, cnt);
  combine_rows<<<16, 256, 0, stream>>>(pmax, psum, diag, lpart, cpart, cnt, out);
}

// Round 12
// 101.456 us; speedup vs baseline: 4.4869x; 1.0153x over previous
//
#include <hip/hip_runtime.h>
#include <cstdint>

typedef __bf16 bf16x8 __attribute__((ext_vector_type(8)));
typedef float floatx4 __attribute__((ext_vector_type(4)));

// M = 4096 rows, C(K) = 256. ROUND 12: per-XCD work queues + bounded steal.
// R10 counters: K-loop over-fetches 3.4x past L2 at ~3 TB/s (the mystery
// ~40 us). R11's pin-with-claim-flags added +12 us of spill-path spin --
// proving dispatch is imbalanced w.r.t. XCDs (spin only triggers then).
// This round: 8 tile queues, queue q = row-band rowb in [8q,8q+8) x all
// colb (per-XCD working set 2.25 MB -> L2-resident; minimal LLC->L2 fetch
// = 18 MB total). Block pops its OWN XCD's queue (s_getreg XCC_ID, m09)
// with ONE atomicAdd -- index<128 IS the claim (no flags, no spin). If
// drained, advance to next queue: <=8 atomicAdds/block, exactly-once and
// full coverage by counting argument. K-loop/epilogue/combine = verified R9.
//
// Staged layout: Xs[rb(32)][s(4)][kk(2)][rowhi(8)][quad(4)][rowlo(16)][8 bf16]
// holding X[row = rb*128+rowhi*16+rowlo][k = s*64+kk*32+quad*8+j].
// Fragment for 16-row group rowhi at K-step (s,kk): lane reads 16 B at
//   Xs + rb*32768 + (s*1024 + kk*512 + rowhi*64 + lane)*8.

#define OFF_X     (0u)
#define OFF_Y     (2u*1024*1024)
#define OFF_PMAX  (4u*1024*1024)
#define OFF_PSUM  (5u*1024*1024)
#define OFF_DIAG  (6u*1024*1024)
#define OFF_LPART (OFF_DIAG + 16384u)
#define OFF_CPART (OFF_LPART + 256u)
#define OFF_CNT   (OFF_CPART + 256u)
// int layout at OFF_CNT: [0]=combine cnt, [16..23]=per-XCD queue counters.

// ---------------------------------------------------------------------------
// K0: fp32 -> staged bf16 (verified, unchanged; block 0 zeroes 64 ints).
// ---------------------------------------------------------------------------
__global__ __launch_bounds__(256) void transpose_stage(
    const float* __restrict__ pred, const float* __restrict__ gt,
    unsigned short* __restrict__ Xs, unsigned short* __restrict__ Ys,
    int* __restrict__ cnt) {
  int blk = blockIdx.x;
  const int t = threadIdx.x;
  if (blk == 0 && t < 64) cnt[t] = 0;
  const float* src;
  unsigned short* dst;
  int slab;
  if (blk < 256) { src = pred; dst = Xs; slab = blk; }
  else           { src = gt;   dst = Ys; slab = blk - 256; }
  const float* sb = src + slab * 4096;
  const int rb = slab >> 3, rowhi = slab & 7;
  #pragma unroll
  for (int half = 0; half < 2; ++half) {
    int c_ = half * 256 + t;
    int rowlo = c_ & 15;
    int quad  = (c_ >> 4) & 3;
    int kk    = (c_ >> 6) & 1;
    int s     = c_ >> 7;
    int k0 = s * 64 + kk * 32 + quad * 8;
    unsigned int packed[4];
    #pragma unroll
    for (int jj = 0; jj < 4; ++jj) {
      unsigned int lohi[2];
      #pragma unroll
      for (int e = 0; e < 2; ++e) {
        float f = sb[(k0 + jj * 2 + e) * 16 + rowlo];
        unsigned int u = __float_as_uint(f);
        lohi[e] = (u + 0x7FFFu + ((u >> 16) & 1u)) >> 16;   // RNE -> bf16
      }
      packed[jj] = lohi[0] | (lohi[1] << 16);
    }
    unsigned short* o = dst + rb * 32768 +
        (unsigned)(s * 1024 + kk * 512 + rowhi * 64 + quad * 16 + rowlo) * 8;
    uint4 v; v.x = packed[0]; v.y = packed[1]; v.z = packed[2]; v.w = packed[3];
    *reinterpret_cast<uint4*>(o) = v;
  }
}

#define KOFF(KS) ((unsigned)((((KS) >> 1) * 1024 + ((KS)&1) * 512)) * 8)

#define LOADF(AR, BR, KS) do {                                               \
    _Pragma("unroll") for (int fr = 0; fr < 4; ++fr)                         \
      AR[fr] = *reinterpret_cast<const bf16x8*>(                             \
          Ab + KOFF(KS) + (unsigned)((hh * 4 + fr) * 64) * 8);               \
    _Pragma("unroll") for (int fc = 0; fc < 4; ++fc)                         \
      BR[fc] = *reinterpret_cast<const bf16x8*>(                             \
          Bb + KOFF(KS) + (unsigned)((ch * 4 + fc) * 64) * 8);               \
  } while (0)

#define MM(AR, BR) do {                                                      \
    _Pragma("unroll") for (int fr = 0; fr < 4; ++fr)                         \
      _Pragma("unroll") for (int fc = 0; fc < 4; ++fc)                       \
        acc[fr][fc] = __builtin_amdgcn_mfma_f32_16x16x32_bf16(               \
            AR[fr], BR[fc], acc[fr][fc], 0, 0, 0);                           \
  } while (0)

#define KLOOP_DBUF() do {                                                    \
    bf16x8 a0[4], b0[4], a1[4], b1[4];                                       \
    LOADF(a0, b0, 0);                                                        \
    LOADF(a1, b1, 1); MM(a0, b0);                                            \
    LOADF(a0, b0, 2); MM(a1, b1);                                            \
    LOADF(a1, b1, 3); MM(a0, b0);                                            \
    LOADF(a0, b0, 4); MM(a1, b1);                                            \
    LOADF(a1, b1, 5); MM(a0, b0);                                            \
    LOADF(a0, b0, 6); MM(a1, b1);                                            \
    LOADF(a1, b1, 7); MM(a0, b0);                                            \
    MM(a1, b1);                                                              \
  } while (0)

// ---------------------------------------------------------------------------
// K1: per-wave 64x64 GEMM tile; tile obtained from this XCD's queue.
// Queue q holds tiles idx in [0,128): rowb = q*8 + (idx>>4), colb = idx&15.
// Per-XCD working set: A band 512 rows (256 KB) + full B (2 MB) -> L2-fits.
// ---------------------------------------------------------------------------
__global__ __launch_bounds__(256, 2) void gemm_wave4(
    const unsigned short* __restrict__ Xs, const unsigned short* __restrict__ Ys,
    float* __restrict__ pmax, float* __restrict__ psum, float* __restrict__ diag,
    int* __restrict__ cnt) {
  const int t = threadIdx.x;
  const int wv = t >> 6, lane = t & 63;

  __shared__ int s_tile;
  if (t == 0) {
    unsigned x;
    asm volatile("s_getreg_b32 %0, hwreg(HW_REG_XCC_ID)" : "=s"(x));
    x &= 7u;
    int* qc = cnt + 16;               // [16..23]
    int tile = -1;
    #pragma unroll 1
    for (int k = 0; k < 8; ++k) {
      int q = (int)((x + (unsigned)k) & 7u);
      int i = atomicAdd(&qc[q], 1);
      if (i < 128) { tile = q * 128 + i; break; }
    }
    s_tile = tile;                    // provably >= 0 (counting argument)
  }
  __syncthreads();
  const int tile = s_tile;
  const int q = tile >> 7, idx = tile & 127;
  const int rowb = q * 8 + (idx >> 4);      // 0..63 (64-row tiles)
  const int colb = idx & 15;                // 0..15 (256-col groups)

  const int hh = rowb & 1, ch = wv & 1;
  const unsigned short* Ab = Xs + (rowb >> 1) * 32768 + (unsigned)lane * 8;
  const unsigned short* Bb = Ys + ((colb << 1) | (wv >> 1)) * 32768 +
                             (unsigned)lane * 8;

  floatx4 acc[4][4];
  const floatx4 zero = {0.f, 0.f, 0.f, 0.f};
  #pragma unroll
  for (int i = 0; i < 4; ++i)
    #pragma unroll
    for (int j = 0; j < 4; ++j) acc[i][j] = zero;

  KLOOP_DBUF();

  const int quad = lane >> 4, lc = lane & 15;

  // Diagonal: wave is on the diagonal iff colb*4 + wv == rowb.
  if (colb * 4 + wv == rowb) {
    #pragma unroll
    for (int fr = 0; fr < 4; ++fr)
      #pragma unroll
      for (int r = 0; r < 4; ++r)
        if (lc == quad * 4 + r)
          diag[rowb * 64 + fr * 16 + lc] = acc[fr][fr][r];
  }

  // Per-row partials over this wave's 64 cols.
  #pragma unroll
  for (int fr = 0; fr < 4; ++fr) {
    #pragma unroll
    for (int r = 0; r < 4; ++r) {
      float v0 = acc[fr][0][r], v1 = acc[fr][1][r];
      float v2 = acc[fr][2][r], v3 = acc[fr][3][r];
      float m = fmaxf(fmaxf(v0, v1), fmaxf(v2, v3));
      #pragma unroll
      for (int sh = 1; sh < 16; sh <<= 1) m = fmaxf(m, __shfl_xor(m, sh, 64));
      float ss = __expf(v0 - m) + __expf(v1 - m) +
                 __expf(v2 - m) + __expf(v3 - m);
      #pragma unroll
      for (int sh = 1; sh < 16; sh <<= 1) ss += __shfl_xor(ss, sh, 64);
      if (lc == 0) {
        int grow = rowb * 64 + fr * 16 + quad * 4 + r;
        int p = grow * 64 + colb * 4 + wv;
        pmax[p] = m; psum[p] = ss;
      }
    }
  }
}

// ---------------------------------------------------------------------------
// K2: per-row combine + fused finalize (verified, unchanged).
// ---------------------------------------------------------------------------
__global__ __launch_bounds__(256) void combine_rows(
    const float* __restrict__ pmax, const float* __restrict__ psum,
    const float* __restrict__ diag,
    float* __restrict__ lpart, float* __restrict__ cpart,
    int* __restrict__ cnt, float* __restrict__ out) {
  int row = blockIdx.x * 256 + threadIdx.x;
  const float* pm = pmax + row * 64;
  const float* ps = psum + row * 64;
  float M = -3.4e38f;
  #pragma unroll 8
  for (int b = 0; b < 64; ++b) M = fmaxf(M, pm[b]);
  float S = 0.f;
  #pragma unroll 8
  for (int b = 0; b < 64; ++b) S += ps[b] * __expf(pm[b] - M);
  float d = diag[row];
  float lossr = logf(S) + M - d;
  float corr = (d == M) ? 1.f : 0.f;
  #pragma unroll
  for (int sh = 1; sh < 64; sh <<= 1) {
    lossr += __shfl_xor(lossr, sh, 64);
    corr  += __shfl_xor(corr,  sh, 64);
  }
  __shared__ float ls[4], cs[4];
  int wave = threadIdx.x >> 6, lane = threadIdx.x & 63;
  if (lane == 0) { ls[wave] = lossr; cs[wave] = corr; }
  __syncthreads();
  if (threadIdx.x == 0) {
    lpart[blockIdx.x] = ls[0] + ls[1] + ls[2] + ls[3];
    cpart[blockIdx.x] = cs[0] + cs[1] + cs[2] + cs[3];
    __threadfence();                     // release per-block partial
    if (atomicAdd(cnt, 1) == 15) {       // last arriver finalizes
      __threadfence();                   // acquire all partials
      float L = 0.f, C = 0.f;
      for (int i = 0; i < 16; ++i) { L += lpart[i]; C += cpart[i]; }
      out[0] = L * (1.f / 4096.f);
      out[1] = C * (100.f / 4096.f);
    }
  }
}

extern "C" void kernel_launch(void* const* d_in, const int* in_sizes, int n_in,
                              void* d_out, int out_size, void* d_ws, size_t ws_size,
                              hipStream_t stream) {
  const float* pred = (const float*)d_in[0];
  const float* gt   = (const float*)d_in[1];
  char* w = (char*)d_ws;
  unsigned short* Xbf = (unsigned short*)(w + OFF_X);
  unsigned short* Ybf = (unsigned short*)(w + OFF_Y);
  float* pmax  = (float*)(w + OFF_PMAX);
  float* psum  = (float*)(w + OFF_PSUM);
  float* diag  = (float*)(w + OFF_DIAG);
  float* lpart = (float*)(w + OFF_LPART);
  float* cpart = (float*)(w + OFF_CPART);
  int*   cnt   = (int*)(w + OFF_CNT);
  float* out   = (float*)d_out;

  transpose_stage<<<512, 256, 0, stream>>>(pred, gt, Xbf, Ybf, cnt);
  gemm_wave4<<<1024, 256, 0, stream>>>(Xbf, Ybf, pmax, psum, diag, cnt);
  combine_rows<<<16, 256, 0, stream>>>(pmax, psum, diag, lpart, cpart, cnt, out);
}

// Round 13
// 90.852 us; speedup vs baseline: 5.0106x; 1.1167x over previous
//
#include <hip/hip_runtime.h>
#include <cstdint>

typedef __bf16 bf16x8 __attribute__((ext_vector_type(8)));
typedef float floatx4 __attribute__((ext_vector_type(4)));

// M = 4096 rows, C(K) = 256. ROUND 13: MLP (memory-level parallelism) fix.
// Key isolation across R7/R10: identical 64 fragment loads run at 4.6 us
// with an XOR sink (MLP~64) but 15.4 us/rep with MFMA consumers (MLP~8-16:
// compiler inserts vmcnt(8) per step) and ~40 us in every full GEMM.
// The beyond-L2 path is latency-bound, not BW-bound; we never had enough
// loads in flight. Fix: FOUR fragment sets -> 32 loads issued before the
// first MFMA, steady 24-32 in flight per wave (~256/CU at 8 resident waves).
// Static b&7 tile mapping (best measured, R6); dynamic claim atomics removed
// (R11/R12: +10-12 us pure overhead, locality gain nil).
//
// Staged layout: Xs[rb(32)][s(4)][kk(2)][rowhi(8)][quad(4)][rowlo(16)][8 bf16]
// holding X[row = rb*128+rowhi*16+rowlo][k = s*64+kk*32+quad*8+j].
// Fragment for 16-row group rowhi at K-step (s,kk): lane reads 16 B at
//   Xs + rb*32768 + (s*1024 + kk*512 + rowhi*64 + lane)*8.

#define OFF_X     (0u)
#define OFF_Y     (2u*1024*1024)
#define OFF_PMAX  (4u*1024*1024)
#define OFF_PSUM  (5u*1024*1024)
#define OFF_DIAG  (6u*1024*1024)
#define OFF_LPART (OFF_DIAG + 16384u)
#define OFF_CPART (OFF_LPART + 256u)
#define OFF_CNT   (OFF_CPART + 256u)   // cnt[0]: combine arrival counter

// ---------------------------------------------------------------------------
// K0: fp32 -> staged bf16 (verified, unchanged). Block 0 zeroes cnt.
// ---------------------------------------------------------------------------
__global__ __launch_bounds__(256) void transpose_stage(
    const float* __restrict__ pred, const float* __restrict__ gt,
    unsigned short* __restrict__ Xs, unsigned short* __restrict__ Ys,
    int* __restrict__ cnt) {
  int blk = blockIdx.x;
  const int t = threadIdx.x;
  if (blk == 0 && t < 33) cnt[t] = 0;
  const float* src;
  unsigned short* dst;
  int slab;
  if (blk < 256) { src = pred; dst = Xs; slab = blk; }
  else           { src = gt;   dst = Ys; slab = blk - 256; }
  const float* sb = src + slab * 4096;
  const int rb = slab >> 3, rowhi = slab & 7;
  #pragma unroll
  for (int half = 0; half < 2; ++half) {
    int c_ = half * 256 + t;
    int rowlo = c_ & 15;
    int quad  = (c_ >> 4) & 3;
    int kk    = (c_ >> 6) & 1;
    int s     = c_ >> 7;
    int k0 = s * 64 + kk * 32 + quad * 8;
    unsigned int packed[4];
    #pragma unroll
    for (int jj = 0; jj < 4; ++jj) {
      unsigned int lohi[2];
      #pragma unroll
      for (int e = 0; e < 2; ++e) {
        float f = sb[(k0 + jj * 2 + e) * 16 + rowlo];
        unsigned int u = __float_as_uint(f);
        lohi[e] = (u + 0x7FFFu + ((u >> 16) & 1u)) >> 16;   // RNE -> bf16
      }
      packed[jj] = lohi[0] | (lohi[1] << 16);
    }
    unsigned short* o = dst + rb * 32768 +
        (unsigned)(s * 1024 + kk * 512 + rowhi * 64 + quad * 16 + rowlo) * 8;
    uint4 v; v.x = packed[0]; v.y = packed[1]; v.z = packed[2]; v.w = packed[3];
    *reinterpret_cast<uint4*>(o) = v;
  }
}

#define KOFF(KS) ((unsigned)((((KS) >> 1) * 1024 + ((KS)&1) * 512)) * 8)

#define LOADF(AR, BR, KS) do {                                               \
    _Pragma("unroll") for (int fr = 0; fr < 4; ++fr)                         \
      AR[fr] = *reinterpret_cast<const bf16x8*>(                             \
          Ab + KOFF(KS) + (unsigned)((hh * 4 + fr) * 64) * 8);               \
    _Pragma("unroll") for (int fc = 0; fc < 4; ++fc)                         \
      BR[fc] = *reinterpret_cast<const bf16x8*>(                             \
          Bb + KOFF(KS) + (unsigned)((ch * 4 + fc) * 64) * 8);               \
  } while (0)

#define MM(AR, BR) do {                                                      \
    _Pragma("unroll") for (int fr = 0; fr < 4; ++fr)                         \
      _Pragma("unroll") for (int fc = 0; fc < 4; ++fc)                       \
        acc[fr][fc] = __builtin_amdgcn_mfma_f32_16x16x32_bf16(               \
            AR[fr], BR[fc], acc[fr][fc], 0, 0, 0);                           \
  } while (0)

// 4-set software pipeline: 32 loads in flight before the first MFMA; each
// MM(Sj) frees Sj's registers which immediately reload for ks=4+j. Steady
// in-flight: 24-32 loads/wave (vs 8 for the 2-set dbuf).
#define KLOOP_PIPE4() do {                                                   \
    bf16x8 A0[4], B0[4], A1[4], B1[4], A2[4], B2[4], A3[4], B3[4];           \
    LOADF(A0, B0, 0); LOADF(A1, B1, 1);                                      \
    LOADF(A2, B2, 2); LOADF(A3, B3, 3);                                      \
    MM(A0, B0); LOADF(A0, B0, 4);                                            \
    MM(A1, B1); LOADF(A1, B1, 5);                                            \
    MM(A2, B2); LOADF(A2, B2, 6);                                            \
    MM(A3, B3); LOADF(A3, B3, 7);                                            \
    MM(A0, B0); MM(A1, B1); MM(A2, B2); MM(A3, B3);                          \
  } while (0)

// ---------------------------------------------------------------------------
// K1: per-wave 64x64 GEMM tile, no LDS, no barriers, 4-set pipelined loads.
// Static mapping (R6): b&7 "xcd" chunking -- best measured variant.
// ---------------------------------------------------------------------------
__global__ __launch_bounds__(256, 2) void gemm_wave5(
    const unsigned short* __restrict__ Xs, const unsigned short* __restrict__ Ys,
    float* __restrict__ pmax, float* __restrict__ psum, float* __restrict__ diag) {
  const int t = threadIdx.x;
  const int wv = t >> 6, lane = t & 63;
  const int b = blockIdx.x;
  const int xcd = b & 7, slot = b >> 3;             // slot 0..127
  const int rowb = ((xcd >> 1) << 4) | (slot & 15); // 0..63 (64-row tiles)
  const int colb = ((xcd & 1) << 3) | (slot >> 4);  // 0..15 (256-col groups)
  const int hh = rowb & 1, ch = wv & 1;
  const unsigned short* Ab = Xs + (rowb >> 1) * 32768 + (unsigned)lane * 8;
  const unsigned short* Bb = Ys + ((colb << 1) | (wv >> 1)) * 32768 +
                             (unsigned)lane * 8;

  floatx4 acc[4][4];
  const floatx4 zero = {0.f, 0.f, 0.f, 0.f};
  #pragma unroll
  for (int i = 0; i < 4; ++i)
    #pragma unroll
    for (int j = 0; j < 4; ++j) acc[i][j] = zero;

  KLOOP_PIPE4();

  const int quad = lane >> 4, lc = lane & 15;

  // Diagonal: wave is on the diagonal iff colb*4 + wv == rowb.
  if (colb * 4 + wv == rowb) {
    #pragma unroll
    for (int fr = 0; fr < 4; ++fr)
      #pragma unroll
      for (int r = 0; r < 4; ++r)
        if (lc == quad * 4 + r)
          diag[rowb * 64 + fr * 16 + lc] = acc[fr][fr][r];
  }

  // Per-row partials over this wave's 64 cols.
  #pragma unroll
  for (int fr = 0; fr < 4; ++fr) {
    #pragma unroll
    for (int r = 0; r < 4; ++r) {
      float v0 = acc[fr][0][r], v1 = acc[fr][1][r];
      float v2 = acc[fr][2][r], v3 = acc[fr][3][r];
      float m = fmaxf(fmaxf(v0, v1), fmaxf(v2, v3));
      #pragma unroll
      for (int sh = 1; sh < 16; sh <<= 1) m = fmaxf(m, __shfl_xor(m, sh, 64));
      float ss = __expf(v0 - m) + __expf(v1 - m) +
                 __expf(v2 - m) + __expf(v3 - m);
      #pragma unroll
      for (int sh = 1; sh < 16; sh <<= 1) ss += __shfl_xor(ss, sh, 64);
      if (lc == 0) {
        int grow = rowb * 64 + fr * 16 + quad * 4 + r;
        int p = grow * 64 + colb * 4 + wv;
        pmax[p] = m; psum[p] = ss;
      }
    }
  }
}

// ---------------------------------------------------------------------------
// K2: per-row combine + fused finalize (verified, unchanged).
// ---------------------------------------------------------------------------
__global__ __launch_bounds__(256) void combine_rows(
    const float* __restrict__ pmax, const float* __restrict__ psum,
    const float* __restrict__ diag,
    float* __restrict__ lpart, float* __restrict__ cpart,
    int* __restrict__ cnt, float* __restrict__ out) {
  int row = blockIdx.x * 256 + threadIdx.x;
  const float* pm = pmax + row * 64;
  const float* ps = psum + row * 64;
  float M = -3.4e38f;
  #pragma unroll 8
  for (int b = 0; b < 64; ++b) M = fmaxf(M, pm[b]);
  float S = 0.f;
  #pragma unroll 8
  for (int b = 0; b < 64; ++b) S += ps[b] * __expf(pm[b] - M);
  float d = diag[row];
  float lossr = logf(S) + M - d;
  float corr = (d == M) ? 1.f : 0.f;
  #pragma unroll
  for (int sh = 1; sh < 64; sh <<= 1) {
    lossr += __shfl_xor(lossr, sh, 64);
    corr  += __shfl_xor(corr,  sh, 64);
  }
  __shared__ float ls[4], cs[4];
  int wave = threadIdx.x >> 6, lane = threadIdx.x & 63;
  if (lane == 0) { ls[wave] = lossr; cs[wave] = corr; }
  __syncthreads();
  if (threadIdx.x == 0) {
    lpart[blockIdx.x] = ls[0] + ls[1] + ls[2] + ls[3];
    cpart[blockIdx.x] = cs[0] + cs[1] + cs[2] + cs[3];
    __threadfence();                     // release per-block partial
    if (atomicAdd(cnt, 1) == 15) {       // last arriver finalizes
      __threadfence();                   // acquire all partials
      float L = 0.f, C = 0.f;
      for (int i = 0; i < 16; ++i) { L += lpart[i]; C += cpart[i]; }
      out[0] = L * (1.f / 4096.f);
      out[1] = C * (100.f / 4096.f);
    }
  }
}

extern "C" void kernel_launch(void* const* d_in, const int* in_sizes, int n_in,
                              void* d_out, int out_size, void* d_ws, size_t ws_size,
                              hipStream_t stream) {
  const float* pred = (const float*)d_in[0];
  const float* gt   = (const float*)d_in[1];
  char* w = (char*)d_ws;
  unsigned short* Xbf = (unsigned short*)(w + OFF_X);
  unsigned short* Ybf = (unsigned short*)(w + OFF_Y);
  float* pmax  = (float*)(w + OFF_PMAX);
  float* psum  = (float*)(w + OFF_PSUM);
  float* diag  = (float*)(w + OFF_DIAG);
  float* lpart = (float*)(w + OFF_LPART);
  float* cpart = (float*)(w + OFF_CPART);
  int*   cnt   = (int*)(w + OFF_CNT);
  float* out   = (float*)d_out;

  transpose_stage<<<512, 256, 0, stream>>>(pred, gt, Xbf, Ybf, cnt);
  gemm_wave5<<<1024, 256, 0, stream>>>(Xbf, Ybf, pmax, psum, diag);
  combine_rows<<<16, 256, 0, stream>>>(pmax, psum, diag, lpart, cpart, cnt, out);
}